// Round 6
// baseline (116.690 us; speedup 1.0000x reference)
//
#include <hip/hip_runtime.h>
#include <hip/hip_fp16.h>
#include <math.h>

#define NN 10000      // nodes
#define NE 320000     // edges
#define NG 64         // graphs
#define DD 256        // feature dim (in == hid)
#define DOUT 16
#define SLOT 96       // padded CSR slots per node (P(deg>96) ~ 1e-20, mean 32)
#define HALFN 5000    // source-partition boundary (2.56 MB window < 4 MiB L2)

typedef __attribute__((ext_vector_type(8))) _Float16 f16x8;
typedef __attribute__((ext_vector_type(4))) float f32x4;

// ---- workspace layout (bytes, 16B aligned) ----
#define OFF_CNTLO 0u            // NN ints (low-source cursor)
#define OFF_CNTHI 40064u        // NN ints (high-source cursor)
#define OFF_CSR   80128u        // NN*SLOT ints (lo grows up, hi grows down)
#define OFF_XH    3920128u      // NN*DD f16
#define OFF_AGGR  9040128u      // NN*DD f16
#define OFF_H1    14160128u     // NN*DD f16
#define OFF_H2    19280128u     // NN*DD f16
#define OFF_WH    24400128u     // 4 * 65536 f16 (w1l, w1r, w2l, w2r)
#define OFF_POOL  24924416u     // NG*DD fp32

// ---------- init: zero cursors + pooled ----------
__global__ __launch_bounds__(256) void init_kernel(int* __restrict__ cntLo,
                                                   int* __restrict__ cntHi,
                                                   float* __restrict__ pooled) {
  int i = blockIdx.x * 256 + threadIdx.x;   // 64 blocks -> 16384 threads
  if (i < NN) { cntLo[i] = 0; cntHi[i] = 0; }
  if (i < NG * DD) pooled[i] = 0.f;
}

// ---------- prep: partitioned padded-CSR fill + fp32->fp16 casts ----------
#define NFB 1250                // fill blocks (NE/256)
#define NXG (NN * DD / 8)       // 320000 x-groups of 8
#define NWG 8192                // groups per weight matrix
#define NCB ((NXG + 4 * NWG + 255) / 256)   // cast blocks
__global__ __launch_bounds__(256) void prep_kernel(
    const int* __restrict__ ei, int* __restrict__ cntLo, int* __restrict__ cntHi,
    int* __restrict__ csr,
    const float* __restrict__ x, const float* __restrict__ w1l,
    const float* __restrict__ w1r, const float* __restrict__ w2l,
    const float* __restrict__ w2r, _Float16* __restrict__ xh,
    _Float16* __restrict__ wh) {
  if (blockIdx.x < NFB) {
    int e = blockIdx.x * 256 + threadIdx.x;
    int s = ei[e];
    int d = ei[NE + e];
    if (s < HALFN) {
      int p = atomicAdd(&cntLo[d], 1);
      if (p < SLOT) csr[d * SLOT + p] = s;            // grow up
    } else {
      int p = atomicAdd(&cntHi[d], 1);
      if (p < SLOT) csr[d * SLOT + SLOT - 1 - p] = s; // grow down
    }
    return;
  }
  int i = (blockIdx.x - NFB) * 256 + threadIdx.x;
  const float* src;
  _Float16* dst;
  if (i < NXG) {
    src = x + i * 8;
    dst = xh + i * 8;
  } else if (i < NXG + 4 * NWG) {
    int j = i - NXG;
    int w = j >> 13, k = j & (NWG - 1);
    src = ((w == 0) ? w1l : (w == 1) ? w1r : (w == 2) ? w2l : w2r) + k * 8;
    dst = wh + w * 65536 + k * 8;
  } else {
    return;
  }
  const float4* sp = (const float4*)src;
  float4 a = sp[0], b = sp[1];
  f16x8 r;
  r[0] = (_Float16)a.x; r[1] = (_Float16)a.y; r[2] = (_Float16)a.z; r[3] = (_Float16)a.w;
  r[4] = (_Float16)b.x; r[5] = (_Float16)b.y; r[6] = (_Float16)b.z; r[7] = (_Float16)b.w;
  *(f16x8*)dst = r;
}

// ---------- mean aggregation: one wave per node, two L2-windowed passes ----------
// Pass A gathers only src<HALFN rows (2.56 MB window), pass B the rest.
// Each window fits per-XCD L2 -> gather runs at L2 BW instead of L3.
__global__ __launch_bounds__(256) void aggregate_f16_kernel(
    const _Float16* __restrict__ xin, const int* __restrict__ cntLo,
    const int* __restrict__ cntHi, const int* __restrict__ csr,
    _Float16* __restrict__ out) {
  const int wave = threadIdx.x >> 6, lane = threadIdx.x & 63;
  const int node = blockIdx.x * 4 + wave;
  if (node >= NN) return;
  const int cLo = cntLo[node], cHi = cntHi[node];
  const int nLo = min(cLo, SLOT);
  const int nHi = min(cHi, SLOT);
  const int base = node * SLOT;
  const int h = lane >> 5;          // half-wave id: one 512B row per half-wave
  const int cb = (lane & 31) * 8;   // channel base (8 ch = 16B per lane)
  float a[8] = {0.f, 0.f, 0.f, 0.f, 0.f, 0.f, 0.f, 0.f};

#define GATHER(LO, HI)                                                        \
  {                                                                           \
    int i = (LO) + h;                                                         \
    for (; i + 14 < (HI); i += 16) {                                          \
      f16x8 v[8];                                                             \
      _Pragma("unroll") for (int u = 0; u < 8; ++u) {                         \
        int s = csr[base + i + 2 * u];                                        \
        v[u] = *(const f16x8*)&xin[s * DD + cb];                              \
      }                                                                       \
      _Pragma("unroll") for (int j = 0; j < 8; ++j)                           \
        a[j] += (((float)v[0][j] + (float)v[1][j]) +                          \
                 ((float)v[2][j] + (float)v[3][j])) +                         \
                (((float)v[4][j] + (float)v[5][j]) +                          \
                 ((float)v[6][j] + (float)v[7][j]));                          \
    }                                                                         \
    for (; i < (HI); i += 2) {                                                \
      int s = csr[base + i];                                                  \
      f16x8 v = *(const f16x8*)&xin[s * DD + cb];                             \
      _Pragma("unroll") for (int j = 0; j < 8; ++j) a[j] += (float)v[j];      \
    }                                                                         \
  }

  GATHER(0, nLo);                 // low-window pass (src < HALFN)
  GATHER(SLOT - nHi, SLOT);       // high-window pass (src >= HALFN)
#undef GATHER

#pragma unroll
  for (int j = 0; j < 8; ++j) a[j] += __shfl_xor(a[j], 32);
  if (lane < 32) {
    float inv = 1.0f / fmaxf((float)(cLo + cHi), 1.0f);
    f16x8 r;
#pragma unroll
    for (int j = 0; j < 8; ++j) r[j] = (_Float16)(a[j] * inv);
    *(f16x8*)&out[node * DD + cb] = r;
  }
}

// ---------- fused SAGE GEMM via MFMA: out = relu([A1|A2] @ [W1;W2]^T + b) ----------
// 128x64 tile, 4 waves, each wave 64x32 (4x2 frags of 16x16x32), BK=64,
// LDS double-buffered, 1 barrier per K-step, reg-staged prefetch.
// 1-D grid of 320 blocks, XCD-swizzled.
__global__ __launch_bounds__(256) void gemm_mfma_kernel(
    const _Float16* __restrict__ A1, const _Float16* __restrict__ A2,
    const _Float16* __restrict__ W1, const _Float16* __restrict__ W2,
    const float* __restrict__ bias, _Float16* __restrict__ out) {
  __shared__ _Float16 As[2][128][72];   // 72 = 64 + 8 pad (144B row stride)
  __shared__ _Float16 Bs[2][64][72];
  const int id = blockIdx.x;
  const int xcd = id & 7;
  const int q = id >> 3;
  const int cblk = q & 3;
  const int rblk = (q >> 2) * 8 + xcd;
  const int row0 = rblk * 128, col0 = cblk * 64;
  if (row0 >= NN) return;               // tail (uniform exit)

  const int t = threadIdx.x;
  const int lane = t & 63;
  const int wid = t >> 6;
  const int wr = wid >> 1, wc = wid & 1;      // wave quadrant: 64 rows x 32 cols
  const int sar = t >> 1, sac = (t & 1) * 32;
  const int sbr = t >> 2, sbc = (t & 3) * 16;
  const int fr = lane & 15;
  const int fk = (lane >> 4) * 8;

  int garow = row0 + sar;
  if (garow >= NN) garow = NN - 1;            // clamp (outputs guarded below)
  const int gbrow = col0 + sbr;

  f32x4 acc[4][2];
#pragma unroll
  for (int m = 0; m < 4; ++m)
#pragma unroll
    for (int n = 0; n < 2; ++n) {
      acc[m][n][0] = 0.f; acc[m][n][1] = 0.f;
      acc[m][n][2] = 0.f; acc[m][n][3] = 0.f;
    }

  f16x8 rA[4], rB[2];

#define LOADSTEP(S)                                                          \
  {                                                                          \
    const _Float16* Ap = ((S) < 4) ? A1 : A2;                                \
    const _Float16* Wp = ((S) < 4) ? W1 : W2;                                \
    const int k0 = ((S) & 3) * 64;                                           \
    _Pragma("unroll") for (int j = 0; j < 4; ++j)                            \
        rA[j] = *(const f16x8*)&Ap[garow * DD + k0 + sac + 8 * j];           \
    _Pragma("unroll") for (int j = 0; j < 2; ++j)                            \
        rB[j] = *(const f16x8*)&Wp[gbrow * DD + k0 + sbc + 8 * j];           \
  }

#define WRITESTEP(B)                                                         \
  {                                                                          \
    _Pragma("unroll") for (int j = 0; j < 4; ++j)                            \
        *(f16x8*)&As[B][sar][sac + 8 * j] = rA[j];                           \
    _Pragma("unroll") for (int j = 0; j < 2; ++j)                            \
        *(f16x8*)&Bs[B][sbr][sbc + 8 * j] = rB[j];                           \
  }

  LOADSTEP(0);
  WRITESTEP(0);
  LOADSTEP(1);
  __syncthreads();

#pragma unroll
  for (int s = 0; s < 8; ++s) {
    const int b = s & 1;
#pragma unroll
    for (int kk = 0; kk < 2; ++kk) {
      f16x8 af[4], bf[2];
#pragma unroll
      for (int m = 0; m < 4; ++m)
        af[m] = *(const f16x8*)&As[b][wr * 64 + m * 16 + fr][kk * 32 + fk];
#pragma unroll
      for (int n = 0; n < 2; ++n)
        bf[n] = *(const f16x8*)&Bs[b][wc * 32 + n * 16 + fr][kk * 32 + fk];
#pragma unroll
      for (int m = 0; m < 4; ++m)
#pragma unroll
        for (int n = 0; n < 2; ++n)
          acc[m][n] = __builtin_amdgcn_mfma_f32_16x16x32_f16(af[m], bf[n], acc[m][n], 0, 0, 0);
    }
    if (s < 7) {
      WRITESTEP(1 - b);
      if (s < 6) LOADSTEP(s + 2);
      __syncthreads();
    }
  }
#undef LOADSTEP
#undef WRITESTEP

  const int orow = row0 + wr * 64 + (lane >> 4) * 4;
  const int ocol = col0 + wc * 32 + fr;
#pragma unroll
  for (int m = 0; m < 4; ++m)
#pragma unroll
    for (int n = 0; n < 2; ++n) {
      int col = ocol + n * 16;
      float bv = bias[col];
#pragma unroll
      for (int j = 0; j < 4; ++j) {
        int row = orow + m * 16 + j;
        if (row < NN) {
          float v = acc[m][n][j] + bv;
          out[row * DD + col] = (_Float16)fmaxf(v, 0.f);
        }
      }
    }
}

// ---------- global add pool: chunked, register-accumulate, atomic flush ----------
__global__ __launch_bounds__(256) void pool_chunk_kernel(const _Float16* __restrict__ h2,
                                                         const int* __restrict__ batch,
                                                         float* __restrict__ pooled) {
  const int c = threadIdx.x;
  const int n0 = blockIdx.x * 16;
  const int n1 = min(n0 + 16, NN);
  if (n0 >= NN) return;
  float acc = 0.f;
  int g = batch[n0];
  for (int i = n0; i < n1; ++i) {
    int gi = batch[i];
    if (gi != g) {
      atomicAdd(&pooled[g * DD + c], acc);
      acc = 0.f;
      g = gi;
    }
    acc += (float)h2[i * DD + c];
  }
  atomicAdd(&pooled[g * DD + c], acc);
}

// ---------- classifier ----------
__global__ __launch_bounds__(256) void cls_kernel(const float* __restrict__ pooled,
                                                  const float* __restrict__ wc,
                                                  const float* __restrict__ bc,
                                                  float* __restrict__ out) {
  int t = blockIdx.x * 256 + threadIdx.x;
  if (t >= NG * DOUT) return;
  int g = t >> 4, j = t & 15;
  float s = bc[j];
  for (int k = 0; k < DD; k += 4) {
    float4 p = *(const float4*)&pooled[g * DD + k];
    float4 w = *(const float4*)&wc[j * DD + k];
    s += p.x * w.x + p.y * w.y + p.z * w.z + p.w * w.w;
  }
  out[t] = 1.0f / (1.0f + expf(-s));
}

extern "C" void kernel_launch(void* const* d_in, const int* in_sizes, int n_in,
                              void* d_out, int out_size, void* d_ws, size_t ws_size,
                              hipStream_t stream) {
  const float* x     = (const float*)d_in[0];
  const int*   ei    = (const int*)d_in[1];
  const int*   batch = (const int*)d_in[2];
  const float* w1_l  = (const float*)d_in[3];
  const float* b1_l  = (const float*)d_in[4];
  const float* w1_r  = (const float*)d_in[5];
  const float* w2_l  = (const float*)d_in[6];
  const float* b2_l  = (const float*)d_in[7];
  const float* w2_r  = (const float*)d_in[8];
  const float* w_cls = (const float*)d_in[9];
  const float* b_cls = (const float*)d_in[10];
  float* out = (float*)d_out;

  char* ws = (char*)d_ws;
  int*       cntLo  = (int*)(ws + OFF_CNTLO);
  int*       cntHi  = (int*)(ws + OFF_CNTHI);
  int*       csr    = (int*)(ws + OFF_CSR);
  _Float16*  xh     = (_Float16*)(ws + OFF_XH);
  _Float16*  aggr   = (_Float16*)(ws + OFF_AGGR);
  _Float16*  h1     = (_Float16*)(ws + OFF_H1);
  _Float16*  h2     = (_Float16*)(ws + OFF_H2);
  _Float16*  wh     = (_Float16*)(ws + OFF_WH);
  float*     pooled = (float*)(ws + OFF_POOL);

  // 1. zero cursors + pooled
  init_kernel<<<64, 256, 0, stream>>>(cntLo, cntHi, pooled);

  // 2. partitioned padded-CSR fill + all fp16 casts (one dispatch)
  prep_kernel<<<NFB + NCB, 256, 0, stream>>>(ei, cntLo, cntHi, csr, x, w1_l,
                                             w1_r, w2_l, w2_r, xh, wh);

  // 3-6. two SAGE layers
  aggregate_f16_kernel<<<(NN + 3) / 4, 256, 0, stream>>>(xh, cntLo, cntHi, csr, aggr);
  gemm_mfma_kernel<<<320, 256, 0, stream>>>(aggr, xh, wh, wh + 65536, b1_l, h1);

  aggregate_f16_kernel<<<(NN + 3) / 4, 256, 0, stream>>>(h1, cntLo, cntHi, csr, aggr);
  gemm_mfma_kernel<<<320, 256, 0, stream>>>(aggr, h1, wh + 2 * 65536, wh + 3 * 65536, b2_l, h2);

  // 7-8. pool + classifier
  pool_chunk_kernel<<<(NN + 15) / 16, 256, 0, stream>>>(h2, batch, pooled);
  cls_kernel<<<4, 256, 0, stream>>>(pooled, w_cls, b_cls, out);
}

// Round 7
// 113.895 us; speedup vs baseline: 1.0245x; 1.0245x over previous
//
#include <hip/hip_runtime.h>
#include <hip/hip_fp16.h>
#include <math.h>

#define NN 10000      // nodes
#define NE 320000     // edges
#define NG 64         // graphs
#define DD 256        // feature dim (in == hid)
#define DOUT 16
#define SLOT 96       // padded CSR slots per node (P(deg>96) ~ 1e-20, mean 32)

typedef __attribute__((ext_vector_type(8))) _Float16 f16x8;
typedef __attribute__((ext_vector_type(4))) float f32x4;

// ---- workspace layout (bytes, 16B aligned) ----
#define OFF_CNT   0u            // NN ints
#define OFF_CSR   40064u        // NN*SLOT ints
#define OFF_XH    3880064u      // NN*DD f16
#define OFF_AGGR  9000064u      // NN*DD f16
#define OFF_H1    14120064u     // NN*DD f16
#define OFF_H2    19240064u     // NN*DD f16
#define OFF_WH    24360064u     // 4 * 65536 f16 (w1l, w1r, w2l, w2r)
#define OFF_POOL  24884352u     // NG*DD fp32

// ---------- init: zero cnt + pooled ----------
__global__ __launch_bounds__(256) void init_kernel(int* __restrict__ cnt,
                                                   float* __restrict__ pooled) {
  int i = blockIdx.x * 256 + threadIdx.x;   // 64 blocks
  if (i < NN) cnt[i] = 0;
  if (i < NG * DD) pooled[i] = 0.f;
}

// ---------- prep: padded-CSR fill + fp32->fp16 casts, one dispatch ----------
#define NFB 1250                // fill blocks (NE/256)
#define NXG (NN * DD / 8)       // 320000 x-groups of 8
#define NWG 8192                // groups per weight matrix
#define NCB ((NXG + 4 * NWG + 255) / 256)   // cast blocks
__global__ __launch_bounds__(256) void prep_kernel(
    const int* __restrict__ ei, int* __restrict__ cnt, int* __restrict__ csr,
    const float* __restrict__ x, const float* __restrict__ w1l,
    const float* __restrict__ w1r, const float* __restrict__ w2l,
    const float* __restrict__ w2r, _Float16* __restrict__ xh,
    _Float16* __restrict__ wh) {
  if (blockIdx.x < NFB) {
    int e = blockIdx.x * 256 + threadIdx.x;
    int s = ei[e];
    int d = ei[NE + e];
    int p = atomicAdd(&cnt[d], 1);
    if (p < SLOT) csr[d * SLOT + p] = s;
    return;
  }
  int i = (blockIdx.x - NFB) * 256 + threadIdx.x;
  const float* src;
  _Float16* dst;
  if (i < NXG) {
    src = x + i * 8;
    dst = xh + i * 8;
  } else if (i < NXG + 4 * NWG) {
    int j = i - NXG;
    int w = j >> 13, k = j & (NWG - 1);
    src = ((w == 0) ? w1l : (w == 1) ? w1r : (w == 2) ? w2l : w2r) + k * 8;
    dst = wh + w * 65536 + k * 8;
  } else {
    return;
  }
  const float4* sp = (const float4*)src;
  float4 a = sp[0], b = sp[1];
  f16x8 r;
  r[0] = (_Float16)a.x; r[1] = (_Float16)a.y; r[2] = (_Float16)a.z; r[3] = (_Float16)a.w;
  r[4] = (_Float16)b.x; r[5] = (_Float16)b.y; r[6] = (_Float16)b.z; r[7] = (_Float16)b.w;
  *(f16x8*)dst = r;
}

// ---------- mean aggregation over ONE channel half (dispatch-level L2 window) ----------
// chbase in {0,128}. The gathered line-set for one half is 2.56 MB < 4 MiB L2,
// and the dispatch boundary phase-separates the two halves globally.
// Wave: 4 lane-quarters x 4 concurrent edges, 16B/lane; shfl_xor(16,32) reduce.
__global__ __launch_bounds__(256) void aggregate_half_kernel(
    const _Float16* __restrict__ xin, const int* __restrict__ cnt,
    const int* __restrict__ csr, _Float16* __restrict__ out, int chbase) {
  const int wave = threadIdx.x >> 6, lane = threadIdx.x & 63;
  const int node = blockIdx.x * 4 + wave;
  if (node >= NN) return;
  const int deg = cnt[node];
  const int n = min(deg, SLOT);
  const int base = node * SLOT;
  const int q = lane >> 4;                    // edge slot 0..3
  const int cb = chbase + (lane & 15) * 8;    // 8 channels = 16B per lane
  float a[8] = {0.f, 0.f, 0.f, 0.f, 0.f, 0.f, 0.f, 0.f};
  int i = q;
  // main: 4 edges/quarter in flight -> 16 loads/wave
  for (; i + 12 < n; i += 16) {
    f16x8 v0 = *(const f16x8*)&xin[csr[base + i     ] * DD + cb];
    f16x8 v1 = *(const f16x8*)&xin[csr[base + i + 4 ] * DD + cb];
    f16x8 v2 = *(const f16x8*)&xin[csr[base + i + 8 ] * DD + cb];
    f16x8 v3 = *(const f16x8*)&xin[csr[base + i + 12] * DD + cb];
#pragma unroll
    for (int j = 0; j < 8; ++j)
      a[j] += ((float)v0[j] + (float)v1[j]) + ((float)v2[j] + (float)v3[j]);
  }
  for (; i + 4 < n; i += 8) {
    f16x8 v0 = *(const f16x8*)&xin[csr[base + i    ] * DD + cb];
    f16x8 v1 = *(const f16x8*)&xin[csr[base + i + 4] * DD + cb];
#pragma unroll
    for (int j = 0; j < 8; ++j) a[j] += (float)v0[j] + (float)v1[j];
  }
  for (; i < n; i += 4) {
    f16x8 v = *(const f16x8*)&xin[csr[base + i] * DD + cb];
#pragma unroll
    for (int j = 0; j < 8; ++j) a[j] += (float)v[j];
  }
#pragma unroll
  for (int j = 0; j < 8; ++j) {
    a[j] += __shfl_xor(a[j], 16);
    a[j] += __shfl_xor(a[j], 32);
  }
  if (lane < 16) {
    float inv = 1.0f / fmaxf((float)deg, 1.0f);
    f16x8 r;
#pragma unroll
    for (int j = 0; j < 8; ++j) r[j] = (_Float16)(a[j] * inv);
    // nontemporal: don't evict the gather window with streaming output
    __builtin_nontemporal_store(r, (f16x8*)&out[node * DD + cb]);
  }
}

// ---------- fused SAGE GEMM via MFMA: out = relu([A1|A2] @ [W1;W2]^T + b) ----------
// 128x64 tile, 4 waves, each wave 64x32 (4x2 frags of 16x16x32), BK=64,
// LDS double-buffered, 1 barrier per K-step, reg-staged prefetch.
// 1-D grid of 320 blocks, XCD-swizzled.
__global__ __launch_bounds__(256) void gemm_mfma_kernel(
    const _Float16* __restrict__ A1, const _Float16* __restrict__ A2,
    const _Float16* __restrict__ W1, const _Float16* __restrict__ W2,
    const float* __restrict__ bias, _Float16* __restrict__ out) {
  __shared__ _Float16 As[2][128][72];   // 72 = 64 + 8 pad (144B row stride)
  __shared__ _Float16 Bs[2][64][72];
  const int id = blockIdx.x;
  const int xcd = id & 7;
  const int q = id >> 3;
  const int cblk = q & 3;
  const int rblk = (q >> 2) * 8 + xcd;
  const int row0 = rblk * 128, col0 = cblk * 64;
  if (row0 >= NN) return;               // tail (uniform exit)

  const int t = threadIdx.x;
  const int lane = t & 63;
  const int wid = t >> 6;
  const int wr = wid >> 1, wc = wid & 1;      // wave quadrant: 64 rows x 32 cols
  const int sar = t >> 1, sac = (t & 1) * 32;
  const int sbr = t >> 2, sbc = (t & 3) * 16;
  const int fr = lane & 15;
  const int fk = (lane >> 4) * 8;

  int garow = row0 + sar;
  if (garow >= NN) garow = NN - 1;            // clamp (outputs guarded below)
  const int gbrow = col0 + sbr;

  f32x4 acc[4][2];
#pragma unroll
  for (int m = 0; m < 4; ++m)
#pragma unroll
    for (int n = 0; n < 2; ++n) {
      acc[m][n][0] = 0.f; acc[m][n][1] = 0.f;
      acc[m][n][2] = 0.f; acc[m][n][3] = 0.f;
    }

  f16x8 rA[4], rB[2];

#define LOADSTEP(S)                                                          \
  {                                                                          \
    const _Float16* Ap = ((S) < 4) ? A1 : A2;                                \
    const _Float16* Wp = ((S) < 4) ? W1 : W2;                                \
    const int k0 = ((S) & 3) * 64;                                           \
    _Pragma("unroll") for (int j = 0; j < 4; ++j)                            \
        rA[j] = *(const f16x8*)&Ap[garow * DD + k0 + sac + 8 * j];           \
    _Pragma("unroll") for (int j = 0; j < 2; ++j)                            \
        rB[j] = *(const f16x8*)&Wp[gbrow * DD + k0 + sbc + 8 * j];           \
  }

#define WRITESTEP(B)                                                         \
  {                                                                          \
    _Pragma("unroll") for (int j = 0; j < 4; ++j)                            \
        *(f16x8*)&As[B][sar][sac + 8 * j] = rA[j];                           \
    _Pragma("unroll") for (int j = 0; j < 2; ++j)                            \
        *(f16x8*)&Bs[B][sbr][sbc + 8 * j] = rB[j];                           \
  }

  LOADSTEP(0);
  WRITESTEP(0);
  LOADSTEP(1);
  __syncthreads();

#pragma unroll
  for (int s = 0; s < 8; ++s) {
    const int b = s & 1;
#pragma unroll
    for (int kk = 0; kk < 2; ++kk) {
      f16x8 af[4], bf[2];
#pragma unroll
      for (int m = 0; m < 4; ++m)
        af[m] = *(const f16x8*)&As[b][wr * 64 + m * 16 + fr][kk * 32 + fk];
#pragma unroll
      for (int n = 0; n < 2; ++n)
        bf[n] = *(const f16x8*)&Bs[b][wc * 32 + n * 16 + fr][kk * 32 + fk];
#pragma unroll
      for (int m = 0; m < 4; ++m)
#pragma unroll
        for (int n = 0; n < 2; ++n)
          acc[m][n] = __builtin_amdgcn_mfma_f32_16x16x32_f16(af[m], bf[n], acc[m][n], 0, 0, 0);
    }
    if (s < 7) {
      WRITESTEP(1 - b);
      if (s < 6) LOADSTEP(s + 2);
      __syncthreads();
    }
  }
#undef LOADSTEP
#undef WRITESTEP

  const int orow = row0 + wr * 64 + (lane >> 4) * 4;
  const int ocol = col0 + wc * 32 + fr;
#pragma unroll
  for (int m = 0; m < 4; ++m)
#pragma unroll
    for (int n = 0; n < 2; ++n) {
      int col = ocol + n * 16;
      float bv = bias[col];
#pragma unroll
      for (int j = 0; j < 4; ++j) {
        int row = orow + m * 16 + j;
        if (row < NN) {
          float v = acc[m][n][j] + bv;
          out[row * DD + col] = (_Float16)fmaxf(v, 0.f);
        }
      }
    }
}

// ---------- global add pool: chunked, register-accumulate, atomic flush ----------
__global__ __launch_bounds__(256) void pool_chunk_kernel(const _Float16* __restrict__ h2,
                                                         const int* __restrict__ batch,
                                                         float* __restrict__ pooled) {
  const int c = threadIdx.x;
  const int n0 = blockIdx.x * 16;
  const int n1 = min(n0 + 16, NN);
  if (n0 >= NN) return;
  float acc = 0.f;
  int g = batch[n0];
  for (int i = n0; i < n1; ++i) {
    int gi = batch[i];
    if (gi != g) {
      atomicAdd(&pooled[g * DD + c], acc);
      acc = 0.f;
      g = gi;
    }
    acc += (float)h2[i * DD + c];
  }
  atomicAdd(&pooled[g * DD + c], acc);
}

// ---------- classifier ----------
__global__ __launch_bounds__(256) void cls_kernel(const float* __restrict__ pooled,
                                                  const float* __restrict__ wc,
                                                  const float* __restrict__ bc,
                                                  float* __restrict__ out) {
  int t = blockIdx.x * 256 + threadIdx.x;
  if (t >= NG * DOUT) return;
  int g = t >> 4, j = t & 15;
  float s = bc[j];
  for (int k = 0; k < DD; k += 4) {
    float4 p = *(const float4*)&pooled[g * DD + k];
    float4 w = *(const float4*)&wc[j * DD + k];
    s += p.x * w.x + p.y * w.y + p.z * w.z + p.w * w.w;
  }
  out[t] = 1.0f / (1.0f + expf(-s));
}

extern "C" void kernel_launch(void* const* d_in, const int* in_sizes, int n_in,
                              void* d_out, int out_size, void* d_ws, size_t ws_size,
                              hipStream_t stream) {
  const float* x     = (const float*)d_in[0];
  const int*   ei    = (const int*)d_in[1];
  const int*   batch = (const int*)d_in[2];
  const float* w1_l  = (const float*)d_in[3];
  const float* b1_l  = (const float*)d_in[4];
  const float* w1_r  = (const float*)d_in[5];
  const float* w2_l  = (const float*)d_in[6];
  const float* b2_l  = (const float*)d_in[7];
  const float* w2_r  = (const float*)d_in[8];
  const float* w_cls = (const float*)d_in[9];
  const float* b_cls = (const float*)d_in[10];
  float* out = (float*)d_out;

  char* ws = (char*)d_ws;
  int*       cnt    = (int*)(ws + OFF_CNT);
  int*       csr    = (int*)(ws + OFF_CSR);
  _Float16*  xh     = (_Float16*)(ws + OFF_XH);
  _Float16*  aggr   = (_Float16*)(ws + OFF_AGGR);
  _Float16*  h1     = (_Float16*)(ws + OFF_H1);
  _Float16*  h2     = (_Float16*)(ws + OFF_H2);
  _Float16*  wh     = (_Float16*)(ws + OFF_WH);
  float*     pooled = (float*)(ws + OFF_POOL);

  // 1. zero cnt + pooled
  init_kernel<<<64, 256, 0, stream>>>(cnt, pooled);

  // 2. padded-CSR fill + all fp16 casts (one dispatch)
  prep_kernel<<<NFB + NCB, 256, 0, stream>>>(ei, cnt, csr, x, w1_l, w1_r,
                                             w2_l, w2_r, xh, wh);

  const int agrid = (NN + 3) / 4;

  // layer 1: channel-halved aggregation (dispatch-level L2 windows) + GEMM
  aggregate_half_kernel<<<agrid, 256, 0, stream>>>(xh, cnt, csr, aggr, 0);
  aggregate_half_kernel<<<agrid, 256, 0, stream>>>(xh, cnt, csr, aggr, 128);
  gemm_mfma_kernel<<<320, 256, 0, stream>>>(aggr, xh, wh, wh + 65536, b1_l, h1);

  // layer 2
  aggregate_half_kernel<<<agrid, 256, 0, stream>>>(h1, cnt, csr, aggr, 0);
  aggregate_half_kernel<<<agrid, 256, 0, stream>>>(h1, cnt, csr, aggr, 128);
  gemm_mfma_kernel<<<320, 256, 0, stream>>>(aggr, h1, wh + 2 * 65536, wh + 3 * 65536, b2_l, h2);

  // pool + classifier
  pool_chunk_kernel<<<(NN + 15) / 16, 256, 0, stream>>>(h2, batch, pooled);
  cls_kernel<<<4, 256, 0, stream>>>(pooled, w_cls, b_cls, out);
}